// Round 4
// baseline (235.907 us; speedup 1.0000x reference)
//
#include <hip/hip_runtime.h>

// Problem: B=16, S=2048, D=1024, MAX_LEN=4096
// out[b,s,d] = x[b,s,d] + (keep[b,s] ? pe[rank[b,s], d] : 0)
// rank = cumsum(keep, axis=1) - 1  (keep = !mask; rank >= 0 wherever keep)

#define BB 16
#define SS 2048
#define DD 1024
#define D4 (DD / 4)                  // 256 float4 per row
#define NROWS (BB * SS)              // 32768 rows
#define ROWS_PER_BLK 8

typedef float f4 __attribute__((ext_vector_type(4)));

// Kernel 1: per-batch prefix sum over keep = !mask. One block per batch row.
// 256 threads x 8 elements = 2048 = S. Writes rank (>=0) or -1 sentinel.
// Harness uploads bool inputs as int32.
__global__ void __launch_bounds__(256)
ranks_kernel(const int* __restrict__ mask, int* __restrict__ ranks) {
    const int b = blockIdx.x;
    const int* m = mask + (size_t)b * SS;
    int* r = ranks + (size_t)b * SS;

    const int tid  = threadIdx.x;
    const int base = tid * 8;

    int vals[8];
    int sum = 0;
#pragma unroll
    for (int i = 0; i < 8; ++i) {
        int keep = (m[base + i] == 0) ? 1 : 0;   // keep = !mask
        vals[i] = keep;
        sum += keep;
    }

    // Inclusive scan of per-thread sums across the wave (width 64).
    const int lane = tid & 63;
    const int wid  = tid >> 6;
    int incl = sum;
#pragma unroll
    for (int off = 1; off < 64; off <<= 1) {
        int n = __shfl_up(incl, off, 64);
        if (lane >= off) incl += n;
    }

    __shared__ int wtot[4];
    if (lane == 63) wtot[wid] = incl;
    __syncthreads();

    int woff = 0;
    for (int w = 0; w < wid; ++w) woff += wtot[w];

    int run = woff + incl - sum;    // exclusive prefix for this thread's chunk
#pragma unroll
    for (int i = 0; i < 8; ++i) {
        run += vals[i];
        r[base + i] = vals[i] ? (run - 1) : -1;  // -1 sentinel where masked
    }
}

// Kernel 2: 8 rows per block, 256 threads = one float4 column per row.
// 8 fully independent {x-load, pe-load, add, store} chains per thread for
// deep memory-level parallelism; rank branches are block-uniform.
__global__ void __launch_bounds__(256)
add_pe_kernel(const f4* __restrict__ x, const f4* __restrict__ pe,
              const int* __restrict__ ranks, f4* __restrict__ out) {
    const int row0 = blockIdx.x * ROWS_PER_BLK;
    const int t    = threadIdx.x;                 // d4 index 0..255
    const int4 ra  = *reinterpret_cast<const int4*>(ranks + row0);
    const int4 rb  = *reinterpret_cast<const int4*>(ranks + row0 + 4);
    const size_t base = (size_t)row0 * D4 + t;

    f4 v[ROWS_PER_BLK];
#pragma unroll
    for (int i = 0; i < ROWS_PER_BLK; ++i)
        v[i] = __builtin_nontemporal_load(&x[base + (size_t)i * D4]);

    const int rk[ROWS_PER_BLK] = {ra.x, ra.y, ra.z, ra.w, rb.x, rb.y, rb.z, rb.w};
#pragma unroll
    for (int i = 0; i < ROWS_PER_BLK; ++i)
        if (rk[i] >= 0) v[i] += pe[rk[i] * D4 + t];

#pragma unroll
    for (int i = 0; i < ROWS_PER_BLK; ++i)
        __builtin_nontemporal_store(v[i], &out[base + (size_t)i * D4]);
}

extern "C" void kernel_launch(void* const* d_in, const int* in_sizes, int n_in,
                              void* d_out, int out_size, void* d_ws, size_t ws_size,
                              hipStream_t stream) {
    const float* x    = (const float*)d_in[0];
    const int*   mask = (const int*)d_in[1];   // bool uploaded as int32
    const float* pe   = (const float*)d_in[2];
    float*       out  = (float*)d_out;
    int*         ranks = (int*)d_ws;           // B*S ints = 128 KiB scratch

    ranks_kernel<<<BB, 256, 0, stream>>>(mask, ranks);

    add_pe_kernel<<<NROWS / ROWS_PER_BLK, 256, 0, stream>>>(
        (const f4*)x, (const f4*)pe, ranks, (f4*)out);
}